// Round 7
// baseline (5370.049 us; speedup 1.0000x reference)
//
#include <hip/hip_runtime.h>

// Luenberger state estimator: T=2048 sequential steps, B=1024 elements.
// R7: TWO waves per element (block=128), 2048 waves total = 2 waves/SIMD.
//   wave 0: f-net (64 hidden units)  -> c_f = h1*Wf2 + bf2/64      (e-free)
//   wave 1: g + k-net (64 units)     -> c_k = e0*(h2*Wk2e + bk2e/64)
//                                            + e1*(h2*Wk2o + bk2o/64)
// Each wave: proven swap32 fold + 5-stage DPP half-reduce; lanes 31/63
// ds_add_f32 their 4 half-sums into 8 shared slots (4-deep parity ring,
// zero-2-ahead), one __syncthreads per step, uniform b64 readback into
// replicated x. Only R6-proven op_sel encodings used.

#define T_STEPS 2048
#define B_SZ    1024
#define NX      8
#define HID     64

typedef float v2f __attribute__((ext_vector_type(2)));

// d = a*b + c
__device__ __forceinline__ v2f pk_fma(v2f a, v2f b, v2f c) {
  v2f d;
  asm("v_pk_fma_f32 %0, %1, %2, %3" : "=v"(d) : "v"(a), "v"(b), "v"(c));
  return d;
}
// acc += a*b
__device__ __forceinline__ void pk_fma_acc(v2f& acc, v2f a, v2f b) {
  asm("v_pk_fma_f32 %0, %1, %2, %0" : "+v"(acc) : "v"(a), "v"(b));
}
// d = splat_hi(a)*b + c   (PROVEN in R6)
__device__ __forceinline__ v2f pk_fma_s0hi(v2f a, v2f b, v2f c) {
  v2f d;
  asm("v_pk_fma_f32 %0, %1, %2, %3 op_sel:[1,0,0] op_sel_hi:[1,1,1]"
      : "=v"(d) : "v"(a), "v"(b), "v"(c));
  return d;
}
// acc += a*splat_lo(b)    (PROVEN in R6)
__device__ __forceinline__ void pk_fma_acc_s1lo(v2f& acc, v2f a, v2f b) {
  asm("v_pk_fma_f32 %0, %1, %2, %0 op_sel:[0,0,0] op_sel_hi:[1,0,1]"
      : "+v"(acc) : "v"(a), "v"(b));
}

__device__ __forceinline__ float tanh_pre(float p) {
  // input pre-scaled by 2*log2(e): tanh(z) = 1 - 2/(2^p + 1)
  float e2 = __builtin_amdgcn_exp2f(p);
  float r  = __builtin_amdgcn_rcpf(e2 + 1.0f);
  return fmaf(-2.0f, r, 1.0f);
}

template <int CTRL, int RMASK>
__device__ __forceinline__ float dpp_add(float acc) {
  int moved = __builtin_amdgcn_update_dpp(0, __float_as_int(acc), CTRL, RMASK, 0xf, true);
  return acc + __int_as_float(moved);
}

// after this, lane 31 = sum(lanes 0..31), lane 63 = sum(lanes 32..63)
__device__ __forceinline__ float half_reduce(float c) {
  c = dpp_add<0x111, 0xf>(c);  // row_shr:1
  c = dpp_add<0x112, 0xf>(c);  // row_shr:2
  c = dpp_add<0x114, 0xf>(c);  // row_shr:4
  c = dpp_add<0x118, 0xf>(c);  // row_shr:8
  c = dpp_add<0x142, 0xa>(c);  // row_bcast:15 into rows 1,3
  return c;
}

__device__ __forceinline__ void swap32(float& a, float& b) {
  asm("v_permlane32_swap_b32 %0, %1" : "+v"(a), "+v"(b));
}

// atomic fp32 add into LDS, compile-time byte offset
#define DS_ADDF(ADDR, V, OFF)                                             \
  asm volatile("ds_add_f32 %0, %1 offset:%c2"                             \
               :: "v"(ADDR), "v"(V), "i"(OFF) : "memory")

__global__ __launch_bounds__(128, 2) void luen_kernel(
    const float* __restrict__ u, const float* __restrict__ y,
    const float* __restrict__ Wf1, const float* __restrict__ bf1,
    const float* __restrict__ Wf2, const float* __restrict__ bf2,
    const float* __restrict__ Wg, const float* __restrict__ bg,
    const float* __restrict__ Wk1, const float* __restrict__ bk1,
    const float* __restrict__ Wk2, const float* __restrict__ bk2,
    float* __restrict__ out) {
  const int tid  = threadIdx.x;
  const int lane = tid & 63;
  const int wid  = __builtin_amdgcn_readfirstlane(tid >> 6);  // wave-uniform
  const int eb   = blockIdx.x;

  const float TS = 2.885390081777927f;  // 2*log2(e)
  const float INV64 = 1.0f / 64.0f;

  // LDS: 4 parity buffers x 8 slots (floats 0..31) + dump zone (32..127)
  __shared__ float sm[128];
  if (tid < 32) sm[tid] = 0.0f;

  // ---- permlane32_swap direction probe (proven R3/R6) ----
  float probe = (lane < 32) ? 0.0f : 1.0f;
  float zf = 0.0f;
  swap32(probe, zf);
  const bool dir1 = __builtin_amdgcn_readlane(__float_as_int(probe), 32) != 0;
  const int laneA = dir1 ? 63 : 31;  // d_j@laneA = S(c_j)     -> slots 0..3
  const int laneB = dir1 ? 31 : 63;  // d_j@laneB = S(c_{j+4}) -> slots 4..7

  // ds_add byte address: contributing lanes hit slots, others hit dump
  int aidx;
  if (lane == laneA)      aidx = 0;        // + PAR*8 + j  (via imm offset)
  else if (lane == laneB) aidx = 4;
  else                    aidx = 32 + lane;
  const int abase = aidx * 4;              // byte address
  // zero-write index: lanes 0..7 -> slots, others -> dump
  const int zidx = (lane < 8) ? lane : (32 + lane);

  // ---- weights (per wid; shared register names to bound pressure) ----
  v2f wA0, wA1, wA2, wA3, wA4, hb;
  v2f wB0, wB1, wB2, wB3, wC0, wC1, wC2, wC3;
  v2f wD0, wD1, wD2, wD3, wE0, wE1, wE2, wE3;
  v2f wg00, wg01, wg02, wg03, wg10, wg11, wg12, wg13, a0i, a1i;
  v2f zz; zz[0] = 0.0f; zz[1] = 0.0f;

  if (wid == 0) {
    wA0 = v2f{TS * Wf1[0 * HID + lane], TS * Wf1[1 * HID + lane]};
    wA1 = v2f{TS * Wf1[2 * HID + lane], TS * Wf1[3 * HID + lane]};
    wA2 = v2f{TS * Wf1[4 * HID + lane], TS * Wf1[5 * HID + lane]};
    wA3 = v2f{TS * Wf1[6 * HID + lane], TS * Wf1[7 * HID + lane]};
    wA4 = v2f{TS * Wf1[8 * HID + lane], TS * Wf1[9 * HID + lane]};
    hb  = v2f{TS * bf1[lane], 0.0f};
    const float* wr = Wf2 + lane * NX;
    wB0 = v2f{wr[0], wr[1]}; wB1 = v2f{wr[2], wr[3]};
    wB2 = v2f{wr[4], wr[5]}; wB3 = v2f{wr[6], wr[7]};
    wC0 = v2f{INV64 * bf2[0], INV64 * bf2[1]};
    wC1 = v2f{INV64 * bf2[2], INV64 * bf2[3]};
    wC2 = v2f{INV64 * bf2[4], INV64 * bf2[5]};
    wC3 = v2f{INV64 * bf2[6], INV64 * bf2[7]};
  } else {
    wA0 = v2f{TS * Wk1[0 * HID + lane], TS * Wk1[1 * HID + lane]};
    wA1 = v2f{TS * Wk1[2 * HID + lane], TS * Wk1[3 * HID + lane]};
    wA2 = v2f{TS * Wk1[4 * HID + lane], TS * Wk1[5 * HID + lane]};
    wA3 = v2f{TS * Wk1[6 * HID + lane], TS * Wk1[7 * HID + lane]};
    hb  = v2f{TS * bk1[lane], 0.0f};
    const float* kr = Wk2 + lane * (NX * 2);
    wB0 = v2f{kr[0], kr[2]};   wB1 = v2f{kr[4], kr[6]};     // Wk2 even cols
    wB2 = v2f{kr[8], kr[10]};  wB3 = v2f{kr[12], kr[14]};
    wC0 = v2f{kr[1], kr[3]};   wC1 = v2f{kr[5], kr[7]};     // Wk2 odd cols
    wC2 = v2f{kr[9], kr[11]};  wC3 = v2f{kr[13], kr[15]};
    wD0 = v2f{INV64 * bk2[0], INV64 * bk2[2]};
    wD1 = v2f{INV64 * bk2[4], INV64 * bk2[6]};
    wD2 = v2f{INV64 * bk2[8], INV64 * bk2[10]};
    wD3 = v2f{INV64 * bk2[12], INV64 * bk2[14]};
    wE0 = v2f{INV64 * bk2[1], INV64 * bk2[3]};
    wE1 = v2f{INV64 * bk2[5], INV64 * bk2[7]};
    wE2 = v2f{INV64 * bk2[9], INV64 * bk2[11]};
    wE3 = v2f{INV64 * bk2[13], INV64 * bk2[15]};
    wg00 = v2f{Wg[0], Wg[2]};   wg10 = v2f{Wg[1], Wg[3]};
    wg01 = v2f{Wg[4], Wg[6]};   wg11 = v2f{Wg[5], Wg[7]};
    wg02 = v2f{Wg[8], Wg[10]};  wg12 = v2f{Wg[9], Wg[11]};
    wg03 = v2f{Wg[12], Wg[14]}; wg13 = v2f{Wg[13], Wg[15]};
    a0i = v2f{bg[0], 0.0f};
    a1i = v2f{bg[1], 0.0f};
  }

  // per-wave input stream: wave0 reads u, wave1 reads y
  const v2f* ps = ((wid == 0) ? reinterpret_cast<const v2f*>(u)
                              : reinterpret_cast<const v2f*>(y)) + eb;
  const int STR = B_SZ;

  v2f x2[4];
#pragma unroll
  for (int p = 0; p < 4; ++p) x2[p] = v2f{0.0f, 0.0f};

  v2f Sa[4], Sb[4];
#define LOADG(S_)                                                  \
  {                                                                \
    S_[0] = ps[0 * STR]; S_[1] = ps[1 * STR];                      \
    S_[2] = ps[2 * STR]; S_[3] = ps[3 * STR];                      \
    ps += 4 * STR;                                                 \
  }

  __syncthreads();  // prologue zero visible

#define STEP(C_, PAR)                                                         \
  {                                                                           \
    const v2f cs = (C_);                                                      \
    v2f cp0, cp1, cp2, cp3;                                                   \
    if (wid == 0) {                                                           \
      /* f-net: pre = [x;u].Wf1 + bf1 (scaled) */                             \
      v2f pf = pk_fma(x2[0], wA0, hb);                                        \
      pk_fma_acc(pf, x2[1], wA1);                                             \
      pk_fma_acc(pf, x2[2], wA2);                                             \
      pk_fma_acc(pf, x2[3], wA3);                                             \
      pk_fma_acc(pf, cs, wA4);                                                \
      const float hv = tanh_pre(pf[0] + pf[1]);                               \
      v2f hs; hs[0] = hv; hs[1] = hv;                                         \
      cp0 = pk_fma(hs, wB0, wC0);                                             \
      cp1 = pk_fma(hs, wB1, wC1);                                             \
      cp2 = pk_fma(hs, wB2, wC2);                                             \
      cp3 = pk_fma(hs, wB3, wC3);                                             \
    } else {                                                                  \
      /* y_hat and packed error ep = {e0,e1} */                               \
      v2f a0 = pk_fma(x2[0], wg00, a0i);                                      \
      v2f a1 = pk_fma(x2[0], wg10, a1i);                                      \
      pk_fma_acc(a0, x2[1], wg01); pk_fma_acc(a1, x2[1], wg11);               \
      pk_fma_acc(a0, x2[2], wg02); pk_fma_acc(a1, x2[2], wg12);               \
      pk_fma_acc(a0, x2[3], wg03); pk_fma_acc(a1, x2[3], wg13);               \
      v2f ep;                                                                 \
      ep[0] = a0[0] + a0[1] - cs[0];                                          \
      ep[1] = a1[0] + a1[1] - cs[1];                                          \
      /* k-net */                                                             \
      v2f pkv = pk_fma(x2[0], wA0, hb);                                       \
      pk_fma_acc(pkv, x2[1], wA1);                                            \
      pk_fma_acc(pkv, x2[2], wA2);                                            \
      pk_fma_acc(pkv, x2[3], wA3);                                            \
      const float hv = tanh_pre(pkv[0] + pkv[1]);                             \
      v2f hs; hs[0] = hv; hs[1] = hv;                                         \
      v2f t0, t1;                                                             \
      t0 = pk_fma(hs, wB0, wD0); t1 = pk_fma(hs, wC0, wE0);                   \
      cp0 = pk_fma_s0hi(ep, t1, zz); pk_fma_acc_s1lo(cp0, t0, ep);            \
      t0 = pk_fma(hs, wB1, wD1); t1 = pk_fma(hs, wC1, wE1);                   \
      cp1 = pk_fma_s0hi(ep, t1, zz); pk_fma_acc_s1lo(cp1, t0, ep);            \
      t0 = pk_fma(hs, wB2, wD2); t1 = pk_fma(hs, wC2, wE2);                   \
      cp2 = pk_fma_s0hi(ep, t1, zz); pk_fma_acc_s1lo(cp2, t0, ep);            \
      t0 = pk_fma(hs, wB3, wD3); t1 = pk_fma(hs, wC3, wE3);                   \
      cp3 = pk_fma_s0hi(ep, t1, zz); pk_fma_acc_s1lo(cp3, t0, ep);            \
    }                                                                         \
    /* PROVEN reduction: swap32 fold + 5-stage half-reduce */                 \
    float c0 = cp0[0], c1 = cp0[1], c2 = cp1[0], c3 = cp1[1];                 \
    float c4 = cp2[0], c5 = cp2[1], c6 = cp3[0], c7 = cp3[1];                 \
    swap32(c0, c4); float d0 = c0 + c4;                                       \
    swap32(c1, c5); float d1 = c1 + c5;                                       \
    swap32(c2, c6); float d2 = c2 + c6;                                       \
    swap32(c3, c7); float d3 = c3 + c7;                                       \
    d0 = half_reduce(d0); d1 = half_reduce(d1);                               \
    d2 = half_reduce(d2); d3 = half_reduce(d3);                               \
    /* cross-wave combine into slots[PAR][0..7] */                            \
    DS_ADDF(abase, d0, ((PAR) * 8 + 0) * 4);                                  \
    DS_ADDF(abase, d1, ((PAR) * 8 + 1) * 4);                                  \
    DS_ADDF(abase, d2, ((PAR) * 8 + 2) * 4);                                  \
    DS_ADDF(abase, d3, ((PAR) * 8 + 3) * 4);                                  \
    /* zero the buffer used two steps ahead (race-free: 4-deep ring) */       \
    sm[zidx + (((PAR) + 2) & 3) * 8] = 0.0f;                                  \
    asm volatile("s_waitcnt lgkmcnt(0)" ::: "memory");                        \
    __syncthreads();                                                          \
    {                                                                         \
      v2f r0 = *(const v2f*)&sm[(PAR) * 8 + 0];                               \
      v2f r1 = *(const v2f*)&sm[(PAR) * 8 + 2];                               \
      v2f r2 = *(const v2f*)&sm[(PAR) * 8 + 4];                               \
      v2f r3 = *(const v2f*)&sm[(PAR) * 8 + 6];                               \
      x2[0] += r0; x2[1] += r1; x2[2] += r2; x2[3] += r3;                     \
    }                                                                         \
  }

  LOADG(Sa);
  LOADG(Sb);

  for (int it = 0; it < 255; ++it) {
    STEP(Sa[0], 0); STEP(Sa[1], 1); STEP(Sa[2], 2); STEP(Sa[3], 3);
    LOADG(Sa);
    STEP(Sb[0], 0); STEP(Sb[1], 1); STEP(Sb[2], 2); STEP(Sb[3], 3);
    LOADG(Sb);
  }
  STEP(Sa[0], 0); STEP(Sa[1], 1); STEP(Sa[2], 2); STEP(Sa[3], 3);
  STEP(Sb[0], 0); STEP(Sb[1], 1); STEP(Sb[2], 2); STEP(Sb[3], 3);
#undef STEP
#undef LOADG

  if (tid == 0) {
#pragma unroll
    for (int p = 0; p < 4; ++p) {
      out[eb * NX + 2 * p]     = x2[p][0];
      out[eb * NX + 2 * p + 1] = x2[p][1];
    }
  }
}

extern "C" void kernel_launch(void* const* d_in, const int* in_sizes, int n_in,
                              void* d_out, int out_size, void* d_ws, size_t ws_size,
                              hipStream_t stream) {
  const float* u   = (const float*)d_in[0];
  const float* y   = (const float*)d_in[1];
  const float* Wf1 = (const float*)d_in[2];
  const float* bf1 = (const float*)d_in[3];
  const float* Wf2 = (const float*)d_in[4];
  const float* bf2 = (const float*)d_in[5];
  const float* Wg  = (const float*)d_in[6];
  const float* bg  = (const float*)d_in[7];
  const float* Wk1 = (const float*)d_in[8];
  const float* bk1 = (const float*)d_in[9];
  const float* Wk2 = (const float*)d_in[10];
  const float* bk2 = (const float*)d_in[11];

  luen_kernel<<<dim3(B_SZ), dim3(2 * HID), 0, stream>>>(
      u, y, Wf1, bf1, Wf2, bf2, Wg, bg, Wk1, bk1, Wk2, bk2, (float*)d_out);
}

// Round 8
// 1002.236 us; speedup vs baseline: 5.3581x; 5.3581x over previous
//
#include <hip/hip_runtime.h>

// Luenberger state estimator: T=2048 sequential steps, B=1024 elements.
// R8 = R6 chassis (proven, 664us) + 2x REDUNDANT WAVES for co-residency:
//   grid = 2048 blocks x 64 threads = 2048 waves = 2 waves/SIMD. Block pairs
//   (2e, 2e+1) compute the SAME element independently (no sync, no LDS);
//   only even blocks store. Co-resident waves fill each other's dependency/
//   hazard stalls (R6 solo-wave: ~244 issue-cy vs 778 cy/step measured).
// R7 post-mortem: per-step cross-wave ds_add+barrier sync = ~5500 cy/step
// overhead -> work-splitting across waves is dead; redundancy is free.

#define T_STEPS 2048
#define B_SZ    1024
#define NX      8
#define HID     64

typedef float v2f __attribute__((ext_vector_type(2)));

// d = a*b + c
__device__ __forceinline__ v2f pk_fma(v2f a, v2f b, v2f c) {
  v2f d;
  asm("v_pk_fma_f32 %0, %1, %2, %3" : "=v"(d) : "v"(a), "v"(b), "v"(c));
  return d;
}
// acc += a*b
__device__ __forceinline__ void pk_fma_acc(v2f& acc, v2f a, v2f b) {
  asm("v_pk_fma_f32 %0, %1, %2, %0" : "+v"(acc) : "v"(a), "v"(b));
}
// d = splat_lo(a)*b + c   (PROVEN R6)
__device__ __forceinline__ v2f pk_fma_s0lo(v2f a, v2f b, v2f c) {
  v2f d;
  asm("v_pk_fma_f32 %0, %1, %2, %3 op_sel:[0,0,0] op_sel_hi:[0,1,1]"
      : "=v"(d) : "v"(a), "v"(b), "v"(c));
  return d;
}
// d = splat_hi(a)*b + c   (PROVEN R6)
__device__ __forceinline__ v2f pk_fma_s0hi(v2f a, v2f b, v2f c) {
  v2f d;
  asm("v_pk_fma_f32 %0, %1, %2, %3 op_sel:[1,0,0] op_sel_hi:[1,1,1]"
      : "=v"(d) : "v"(a), "v"(b), "v"(c));
  return d;
}
// acc += a*splat_lo(b)    (PROVEN R6)
__device__ __forceinline__ void pk_fma_acc_s1lo(v2f& acc, v2f a, v2f b) {
  asm("v_pk_fma_f32 %0, %1, %2, %0 op_sel:[0,0,0] op_sel_hi:[1,0,1]"
      : "+v"(acc) : "v"(a), "v"(b));
}
// acc += a*splat_hi(b)    (PROVEN R6)
__device__ __forceinline__ void pk_fma_acc_s1hi(v2f& acc, v2f a, v2f b) {
  asm("v_pk_fma_f32 %0, %1, %2, %0 op_sel:[0,1,0] op_sel_hi:[1,1,1]"
      : "+v"(acc) : "v"(a), "v"(b));
}

// tanh pair: inputs pre-scaled by 2*log2(e); returns {tanh(a), tanh(b)}
__device__ __forceinline__ v2f tanh_pair(float pa, float pb) {
  v2f r;
  r[0] = __builtin_amdgcn_rcpf(__builtin_amdgcn_exp2f(pa) + 1.0f);
  r[1] = __builtin_amdgcn_rcpf(__builtin_amdgcn_exp2f(pb) + 1.0f);
  v2f h;
  h[0] = fmaf(-2.0f, r[0], 1.0f);
  h[1] = fmaf(-2.0f, r[1], 1.0f);
  return h;
}

template <int CTRL, int RMASK>
__device__ __forceinline__ float dpp_add(float acc) {
  int moved = __builtin_amdgcn_update_dpp(0, __float_as_int(acc), CTRL, RMASK, 0xf, true);
  return acc + __int_as_float(moved);
}

// after this, lane 31 = sum(lanes 0..31), lane 63 = sum(lanes 32..63)
__device__ __forceinline__ float half_reduce(float c) {
  c = dpp_add<0x111, 0xf>(c);  // row_shr:1
  c = dpp_add<0x112, 0xf>(c);  // row_shr:2
  c = dpp_add<0x114, 0xf>(c);  // row_shr:4
  c = dpp_add<0x118, 0xf>(c);  // row_shr:8
  c = dpp_add<0x142, 0xa>(c);  // row_bcast:15 into rows 1,3
  return c;
}

__device__ __forceinline__ void swap32(float& a, float& b) {
  asm("v_permlane32_swap_b32 %0, %1" : "+v"(a), "+v"(b));
}

__device__ __forceinline__ float rlf(float v, int lane) {
  return __int_as_float(__builtin_amdgcn_readlane(__float_as_int(v), lane));
}

__global__ __launch_bounds__(64, 2) void luen_kernel(
    const float* __restrict__ u, const float* __restrict__ y,
    const float* __restrict__ Wf1, const float* __restrict__ bf1,
    const float* __restrict__ Wf2, const float* __restrict__ bf2,
    const float* __restrict__ Wg, const float* __restrict__ bg,
    const float* __restrict__ Wk1, const float* __restrict__ bk1,
    const float* __restrict__ Wk2, const float* __restrict__ bk2,
    float* __restrict__ out) {
  const int eb = blockIdx.x >> 1;   // block pairs compute the same element
  const int h  = threadIdx.x;

  const float TS = 2.885390081777927f;  // 2*log2(e)
  const float INV64 = 1.0f / 64.0f;

  // ---- per-lane weight columns (canonical order) ----
  v2f wf1p[5];
#pragma unroll
  for (int p = 0; p < 5; ++p)
    wf1p[p] = v2f{TS * Wf1[(2 * p) * HID + h], TS * Wf1[(2 * p + 1) * HID + h]};
  v2f wk1p[4];
#pragma unroll
  for (int p = 0; p < 4; ++p)
    wk1p[p] = v2f{TS * Wk1[(2 * p) * HID + h], TS * Wk1[(2 * p + 1) * HID + h]};

  v2f wf2p[4], bf2sp[4];
#pragma unroll
  for (int p = 0; p < 4; ++p) {
    wf2p[p]  = v2f{Wf2[h * NX + 2 * p], Wf2[h * NX + 2 * p + 1]};
    bf2sp[p] = v2f{INV64 * bf2[2 * p], INV64 * bf2[2 * p + 1]};
  }
  v2f wk2e[4], wk2o[4], bk2se[4], bk2so[4];
#pragma unroll
  for (int p = 0; p < 4; ++p) {
    const float* r = Wk2 + h * (NX * 2);
    wk2e[p]  = v2f{r[4 * p], r[4 * p + 2]};
    wk2o[p]  = v2f{r[4 * p + 1], r[4 * p + 3]};
    bk2se[p] = v2f{INV64 * bk2[4 * p], INV64 * bk2[4 * p + 2]};
    bk2so[p] = v2f{INV64 * bk2[4 * p + 1], INV64 * bk2[4 * p + 3]};
  }
  v2f wgc0[4], wgc1[4];
#pragma unroll
  for (int p = 0; p < 4; ++p) {
    wgc0[p] = v2f{Wg[4 * p], Wg[4 * p + 2]};
    wgc1[p] = v2f{Wg[4 * p + 1], Wg[4 * p + 3]};
  }
  const v2f a0i = v2f{bg[0], 0.0f};
  const v2f a1i = v2f{bg[1], 0.0f};
  const v2f pfi = v2f{TS * bf1[h], 0.0f};
  const v2f pki = v2f{TS * bk1[h], 0.0f};

  // ---- permlane32_swap direction probe (one-time; proven) ----
  float probe = (h < 32) ? 0.0f : 1.0f;
  float zf = 0.0f;
  swap32(probe, zf);
  const bool dir1 = __builtin_amdgcn_readlane(__float_as_int(probe), 32) != 0;
  const int laneA = dir1 ? 63 : 31;  // sum of c[j]
  const int laneB = dir1 ? 31 : 63;  // sum of c[j+4]

  const v2f* __restrict__ pu = reinterpret_cast<const v2f*>(u) + eb;
  const v2f* __restrict__ py = reinterpret_cast<const v2f*>(y) + eb;
  const int STR = B_SZ;

  v2f x2[4];
#pragma unroll
  for (int p = 0; p < 4; ++p) x2[p] = v2f{0.0f, 0.0f};

  v2f Au[4], Ay[4], Bu[4], By[4];

#define LOADG(SET_u, SET_y)                          \
  {                                                  \
    SET_u[0] = pu[0 * STR]; SET_u[1] = pu[1 * STR];  \
    SET_u[2] = pu[2 * STR]; SET_u[3] = pu[3 * STR];  \
    SET_y[0] = py[0 * STR]; SET_y[1] = py[1 * STR];  \
    SET_y[2] = py[2 * STR]; SET_y[3] = py[3 * STR];  \
    pu += 4 * STR; py += 4 * STR;                    \
  }

#define STEP(CU_, CY_)                                                        \
  {                                                                           \
    const v2f cu = (CU_);                                                     \
    const v2f cy = (CY_);                                                     \
    /* y_hat and packed error ep = {e0, e1} */                                \
    v2f a0 = pk_fma(x2[0], wgc0[0], a0i);                                     \
    v2f a1 = pk_fma(x2[0], wgc1[0], a1i);                                     \
    pk_fma_acc(a0, x2[1], wgc0[1]); pk_fma_acc(a1, x2[1], wgc1[1]);           \
    pk_fma_acc(a0, x2[2], wgc0[2]); pk_fma_acc(a1, x2[2], wgc1[2]);           \
    pk_fma_acc(a0, x2[3], wgc0[3]); pk_fma_acc(a1, x2[3], wgc1[3]);           \
    v2f ep;                                                                   \
    ep[0] = a0[0] + a0[1] - cy[0];                                            \
    ep[1] = a1[0] + a1[1] - cy[1];                                            \
    /* f-net / k-net pre-activations -> packed hp = {h1, h2} */               \
    v2f pf = pk_fma(x2[0], wf1p[0], pfi);                                     \
    pk_fma_acc(pf, x2[1], wf1p[1]);                                           \
    pk_fma_acc(pf, x2[2], wf1p[2]);                                           \
    pk_fma_acc(pf, x2[3], wf1p[3]);                                           \
    pk_fma_acc(pf, cu, wf1p[4]);                                              \
    v2f pkv = pk_fma(x2[0], wk1p[0], pki);                                    \
    pk_fma_acc(pkv, x2[1], wk1p[1]);                                          \
    pk_fma_acc(pkv, x2[2], wk1p[2]);                                          \
    pk_fma_acc(pkv, x2[3], wk1p[3]);                                          \
    const v2f hp = tanh_pair(pf[0] + pf[1], pkv[0] + pkv[1]);                 \
    /* per-lane contributions: op_sel splats of hp / ep (proven R6) */        \
    float c0, c1, c2, c3, c4, c5, c6, c7;                                     \
    {                                                                         \
      v2f t0 = pk_fma_s0hi(hp, wk2e[0], bk2se[0]);                            \
      v2f t1 = pk_fma_s0hi(hp, wk2o[0], bk2so[0]);                            \
      v2f cp = pk_fma_s0lo(hp, wf2p[0], bf2sp[0]);                            \
      pk_fma_acc_s1lo(cp, t0, ep);                                            \
      pk_fma_acc_s1hi(cp, t1, ep);                                            \
      c0 = cp[0]; c1 = cp[1];                                                 \
    }                                                                         \
    {                                                                         \
      v2f t0 = pk_fma_s0hi(hp, wk2e[1], bk2se[1]);                            \
      v2f t1 = pk_fma_s0hi(hp, wk2o[1], bk2so[1]);                            \
      v2f cp = pk_fma_s0lo(hp, wf2p[1], bf2sp[1]);                            \
      pk_fma_acc_s1lo(cp, t0, ep);                                            \
      pk_fma_acc_s1hi(cp, t1, ep);                                            \
      c2 = cp[0]; c3 = cp[1];                                                 \
    }                                                                         \
    {                                                                         \
      v2f t0 = pk_fma_s0hi(hp, wk2e[2], bk2se[2]);                            \
      v2f t1 = pk_fma_s0hi(hp, wk2o[2], bk2so[2]);                            \
      v2f cp = pk_fma_s0lo(hp, wf2p[2], bf2sp[2]);                            \
      pk_fma_acc_s1lo(cp, t0, ep);                                            \
      pk_fma_acc_s1hi(cp, t1, ep);                                            \
      c4 = cp[0]; c5 = cp[1];                                                 \
    }                                                                         \
    {                                                                         \
      v2f t0 = pk_fma_s0hi(hp, wk2e[3], bk2se[3]);                            \
      v2f t1 = pk_fma_s0hi(hp, wk2o[3], bk2so[3]);                            \
      v2f cp = pk_fma_s0lo(hp, wf2p[3], bf2sp[3]);                            \
      pk_fma_acc_s1lo(cp, t0, ep);                                            \
      pk_fma_acc_s1hi(cp, t1, ep);                                            \
      c6 = cp[0]; c7 = cp[1];                                                 \
    }                                                                         \
    /* PROVEN reduction: swap32 fold + 5-stage half-reduce */                 \
    swap32(c0, c4); float d0 = c0 + c4;                                       \
    swap32(c1, c5); float d1 = c1 + c5;                                       \
    swap32(c2, c6); float d2 = c2 + c6;                                       \
    swap32(c3, c7); float d3 = c3 + c7;                                       \
    d0 = half_reduce(d0); d1 = half_reduce(d1);                               \
    d2 = half_reduce(d2); d3 = half_reduce(d3);                               \
    x2[0][0] += rlf(d0, laneA);                                               \
    x2[0][1] += rlf(d1, laneA);                                               \
    x2[1][0] += rlf(d2, laneA);                                               \
    x2[1][1] += rlf(d3, laneA);                                               \
    x2[2][0] += rlf(d0, laneB);                                               \
    x2[2][1] += rlf(d1, laneB);                                               \
    x2[3][0] += rlf(d2, laneB);                                               \
    x2[3][1] += rlf(d3, laneB);                                               \
  }

  LOADG(Au, Ay);
  LOADG(Bu, By);

  for (int it = 0; it < 255; ++it) {
    STEP(Au[0], Ay[0]); STEP(Au[1], Ay[1]); STEP(Au[2], Ay[2]); STEP(Au[3], Ay[3]);
    LOADG(Au, Ay);
    STEP(Bu[0], By[0]); STEP(Bu[1], By[1]); STEP(Bu[2], By[2]); STEP(Bu[3], By[3]);
    LOADG(Bu, By);
  }
  STEP(Au[0], Ay[0]); STEP(Au[1], Ay[1]); STEP(Au[2], Ay[2]); STEP(Au[3], Ay[3]);
  STEP(Bu[0], By[0]); STEP(Bu[1], By[1]); STEP(Bu[2], By[2]); STEP(Bu[3], By[3]);
#undef STEP
#undef LOADG

  // both waves of a pair hold identical results; only even blocks store
  if (h == 0 && (blockIdx.x & 1) == 0) {
#pragma unroll
    for (int p = 0; p < 4; ++p) {
      out[eb * NX + 2 * p]     = x2[p][0];
      out[eb * NX + 2 * p + 1] = x2[p][1];
    }
  }
}

extern "C" void kernel_launch(void* const* d_in, const int* in_sizes, int n_in,
                              void* d_out, int out_size, void* d_ws, size_t ws_size,
                              hipStream_t stream) {
  const float* u   = (const float*)d_in[0];
  const float* y   = (const float*)d_in[1];
  const float* Wf1 = (const float*)d_in[2];
  const float* bf1 = (const float*)d_in[3];
  const float* Wf2 = (const float*)d_in[4];
  const float* bf2 = (const float*)d_in[5];
  const float* Wg  = (const float*)d_in[6];
  const float* bg  = (const float*)d_in[7];
  const float* Wk1 = (const float*)d_in[8];
  const float* bk1 = (const float*)d_in[9];
  const float* Wk2 = (const float*)d_in[10];
  const float* bk2 = (const float*)d_in[11];

  luen_kernel<<<dim3(2 * B_SZ), dim3(HID), 0, stream>>>(
      u, y, Wf1, bf1, Wf2, bf2, Wg, bg, Wk1, bk1, Wk2, bk2, (float*)d_out);
}